// Round 4
// baseline (189.039 us; speedup 1.0000x reference)
//
#include <hip/hip_runtime.h>
#include <stdint.h>

#define D_MODEL 1024
#define NHEAD   16
#define DHEAD   64
#define BATCH   4
#define SEQ     2048
#define MTOT    (BATCH*SEQ)   // 8192

typedef __attribute__((ext_vector_type(4))) float f32x4;
typedef __attribute__((ext_vector_type(8))) short bf16x8;

typedef __attribute__((address_space(3))) uint32_t lds_u32;
typedef const __attribute__((address_space(1))) uint32_t glb_u32;

__device__ static inline void gload_lds16(const void* g, void* l) {
    __builtin_amdgcn_global_load_lds((glb_u32*)g, (lds_u32*)l, 16, 0, 0);
}

__device__ static inline ushort f2bf(float f) {
    uint32_t u = __builtin_bit_cast(uint32_t, f);
    u += 0x7fffu + ((u >> 16) & 1u);   // RNE (inputs are finite)
    return (ushort)(u >> 16);
}

__device__ static inline float exp2_fast(float x) {
    float r; asm("v_exp_f32 %0, %1" : "=v"(r) : "v"(x)); return r;
}
__device__ static inline uint32_t cvt_pk_bf16(float a, float b) {
    uint32_t r;  // low half = bf16(a), high half = bf16(b)
    asm("v_cvt_pk_bf16_f32 %0, %1, %2" : "=v"(r) : "v"(a), "v"(b));
    return r;
}

// ---------------------------------------------------------------- convert
__global__ __launch_bounds__(256) void convert_kernel(
    const float4* __restrict__ x,
    const float4* __restrict__ wq, const float4* __restrict__ wk,
    const float4* __restrict__ wv, const float4* __restrict__ wo,
    ushort4* __restrict__ xb, ushort4* __restrict__ wb)
{
    const int NX4 = (MTOT * D_MODEL) / 4;
    const int NW4 = (D_MODEL * D_MODEL) / 4;
    const int TOT = NX4 + 4 * NW4;
    for (int i = blockIdx.x * blockDim.x + threadIdx.x; i < TOT;
         i += gridDim.x * blockDim.x) {
        float4 v; ushort4* dst;
        if (i < NX4) { v = x[i]; dst = &xb[i]; }
        else {
            int j = i - NX4;
            int w = j >> 18;
            int r = j & (NW4 - 1);
            const float4* s = (w == 0) ? wq : (w == 1) ? wk : (w == 2) ? wv : wo;
            v = s[r]; dst = &wb[(size_t)w * NW4 + r];
        }
        ushort4 o;
        o.x = f2bf(v.x); o.y = f2bf(v.y); o.z = f2bf(v.z); o.w = f2bf(v.w);
        *dst = o;
    }
}

// ---------------------------------------------------------------- fused QKV GEMM
// W3 = [Wq;Wk;Wv] rows 0..3071.  C[i,e] = x[i,:]·W3[e,:] + bias
// region 0 (Q): *qscale, out [B,H,S,Dh]; region 1 (K): out [B,H,S,Dh];
// region 2 (V): out [B,H,Dh,S] (transposed).
__global__ __launch_bounds__(256) void gemm_qkv(
    const ushort* __restrict__ A,    // [8192,1024] bf16
    const ushort* __restrict__ W3,   // [3072,1024] bf16
    const float* __restrict__ bq, const float* __restrict__ bk,
    const float* __restrict__ bv,
    ushort* __restrict__ Qb, ushort* __restrict__ Kb, ushort* __restrict__ Vtb,
    float qscale)
{
    __shared__ __align__(16) ushort As[128 * 32];
    __shared__ __align__(16) ushort Bs[128 * 32];

    const int tid = threadIdx.x;
    const int w  = tid >> 6, l = tid & 63, lo = l & 15, hi = l >> 4;
    const int wr = w >> 1, wc = w & 1;

    const int id = blockIdx.x;                         // 0..1535
    const int mb = ((id & 7) << 3) | ((id >> 3) & 7);  // 0..63 (XCD-chunked)
    const int nb = id >> 6;                            // 0..23
    const int m0 = mb * 128, n0 = nb * 128;

    f32x4 acc[4][4] = {};
    const int srow = l >> 2;
    const int sk   = (l & 3) * 8;

    for (int kt = 0; kt < 32; ++kt) {
        const int k0 = kt * 32;
        __syncthreads();
#pragma unroll
        for (int c = 0; c < 2; ++c) {
            const int row = c * 64 + w * 16 + srow;
            gload_lds16(&A[(size_t)(m0 + row) * 1024 + k0 + sk],
                        &As[(c * 64 + w * 16) * 32]);
            gload_lds16(&W3[(size_t)(n0 + row) * 1024 + k0 + sk],
                        &Bs[(c * 64 + w * 16) * 32]);
        }
        __syncthreads();

        bf16x8 af[4], bfr[4];
#pragma unroll
        for (int mi = 0; mi < 4; ++mi)
            af[mi] = *(const bf16x8*)&As[(wr * 64 + mi * 16 + lo) * 32 + hi * 8];
#pragma unroll
        for (int ni = 0; ni < 4; ++ni)
            bfr[ni] = *(const bf16x8*)&Bs[(wc * 64 + ni * 16 + lo) * 32 + hi * 8];
#pragma unroll
        for (int mi = 0; mi < 4; ++mi)
#pragma unroll
            for (int ni = 0; ni < 4; ++ni)
                acc[mi][ni] = __builtin_amdgcn_mfma_f32_16x16x32_bf16(
                    af[mi], bfr[ni], acc[mi][ni], 0, 0, 0);
    }

    const int region = nb >> 3;         // 0:Q 1:K 2:V (block-uniform)
    const float scale = (region == 0) ? qscale : 1.0f;
    const float* bias = (region == 0) ? bq : (region == 1) ? bk : bv;
    ushort* outQK = (region == 0) ? Qb : Kb;

#pragma unroll
    for (int mi = 0; mi < 4; ++mi) {
#pragma unroll
        for (int ni = 0; ni < 4; ++ni) {
            const int gj  = n0 + wc * 64 + ni * 16 + lo;   // 0..3071
            const int lcl = gj & 1023;
            const int h = lcl >> 6, dh = lcl & 63;
            const float bj = bias[lcl];
            if (region < 2) {
#pragma unroll
                for (int r = 0; r < 4; ++r) {
                    const int gi = m0 + wr * 64 + mi * 16 + hi * 4 + r;
                    const int b = gi >> 11, s = gi & (SEQ - 1);
                    outQK[(((size_t)(b * NHEAD + h)) * SEQ + s) * DHEAD + dh] =
                        f2bf((acc[mi][ni][r] + bj) * scale);
                }
            } else {
                const int gi0 = m0 + wr * 64 + mi * 16 + hi * 4;
                const int b = gi0 >> 11, s = gi0 & (SEQ - 1);
                ushort4 o4;
                o4.x = f2bf(acc[mi][ni][0] + bj);
                o4.y = f2bf(acc[mi][ni][1] + bj);
                o4.z = f2bf(acc[mi][ni][2] + bj);
                o4.w = f2bf(acc[mi][ni][3] + bj);
                *(ushort4*)&Vtb[(((size_t)(b * NHEAD + h)) * DHEAD + dh) * SEQ + s] = o4;
            }
        }
    }
}

// ---------------------------------------------------------------- output GEMM
__global__ __launch_bounds__(256) void gemm_out(
    const ushort* __restrict__ A,
    const ushort* __restrict__ W,
    const float*  __restrict__ bias,
    float* __restrict__ out)
{
    __shared__ __align__(16) ushort As[128 * 32];
    __shared__ __align__(16) ushort Bs[128 * 32];

    const int tid = threadIdx.x;
    const int w  = tid >> 6, l = tid & 63, lo = l & 15, hi = l >> 4;
    const int wr = w >> 1, wc = w & 1;

    const int id = blockIdx.y * 8 + blockIdx.x;        // 0..511
    const int mb = ((id & 7) << 3) | ((id >> 3) & 7);
    const int nb = id >> 6;
    const int m0 = mb * 128, n0 = nb * 128;

    f32x4 acc[4][4] = {};
    const int srow = l >> 2;
    const int sk   = (l & 3) * 8;

    for (int kt = 0; kt < 32; ++kt) {
        const int k0 = kt * 32;
        __syncthreads();
#pragma unroll
        for (int c = 0; c < 2; ++c) {
            const int row = c * 64 + w * 16 + srow;
            gload_lds16(&A[(size_t)(m0 + row) * 1024 + k0 + sk],
                        &As[(c * 64 + w * 16) * 32]);
            gload_lds16(&W[(size_t)(n0 + row) * 1024 + k0 + sk],
                        &Bs[(c * 64 + w * 16) * 32]);
        }
        __syncthreads();

        bf16x8 af[4], bfr[4];
#pragma unroll
        for (int mi = 0; mi < 4; ++mi)
            af[mi] = *(const bf16x8*)&As[(wr * 64 + mi * 16 + lo) * 32 + hi * 8];
#pragma unroll
        for (int ni = 0; ni < 4; ++ni)
            bfr[ni] = *(const bf16x8*)&Bs[(wc * 64 + ni * 16 + lo) * 32 + hi * 8];
#pragma unroll
        for (int mi = 0; mi < 4; ++mi)
#pragma unroll
            for (int ni = 0; ni < 4; ++ni)
                acc[mi][ni] = __builtin_amdgcn_mfma_f32_16x16x32_bf16(
                    af[mi], bfr[ni], acc[mi][ni], 0, 0, 0);
    }

#pragma unroll
    for (int mi = 0; mi < 4; ++mi)
#pragma unroll
        for (int ni = 0; ni < 4; ++ni) {
            const int gj = n0 + wc * 64 + ni * 16 + lo;
            const float bj = bias[gj];
#pragma unroll
            for (int r = 0; r < 4; ++r) {
                const int gi = m0 + wr * 64 + mi * 16 + hi * 4 + r;
                out[(size_t)gi * D_MODEL + gj] = acc[mi][ni][r] + bj;
            }
        }
}

// ---------------------------------------------------------------- attention
// Swapped-QK^T flash attention, exp2 domain (Q pre-scaled by log2e/8).
// QBLK=64 (4 waves x 16 q-rows). Each block: one (b,h), Q-tile pair {j,31-j}
// -> uniform 33 KV-tiles/block, 1024 blocks (4/CU).
// LDS [64][64] bf16, 16B-granule XOR swizzle.
__global__ __launch_bounds__(256) void attn_kernel(
    const ushort* __restrict__ Q, const ushort* __restrict__ K,
    const ushort* __restrict__ Vt, ushort* __restrict__ ctx)
{
    __shared__ __align__(16) ushort Ks[64 * 64];
    __shared__ __align__(16) ushort Vs[64 * 64];
    __shared__ __align__(16) ushort Pq[4 * 16 * 64];

    const int tid = threadIdx.x;
    const int w = tid >> 6, l = tid & 63, lo = l & 15, hi = l >> 4;
    const int sw = lo & 7;

    const int fid = blockIdx.x;            // 0..1023
    const int xcd = fid & 7;
    const int u = fid >> 3;                // 0..127
    const int g = xcd * 8 + (u & 7);       // bh; g>>3 == xcd
    const int b = g >> 4, h = g & 15;
    const int j = u >> 3;                  // 0..15 (pair index)
    const size_t base = (size_t)(b * NHEAD + h) * SEQ * DHEAD;

    const int krow = tid >> 3;             // 0..31
    const int kcol = (tid & 7) * 8;
    char* PqW = (char*)&Pq[w * 1024];

    for (int pass = 0; pass < 2; ++pass) {
        const int qt = pass ? (31 - j) : j;
        const int q0 = qt << 6;
        const int qw0 = q0 + w * 16;       // this wave's 16 q-rows

        bf16x8 qf[2];
#pragma unroll
        for (int ks = 0; ks < 2; ++ks)
            qf[ks] = *(const bf16x8*)&Q[base +
                (size_t)(qw0 + lo) * DHEAD + ks * 32 + hi * 8];

        f32x4 o[4] = {};
        float mrow = -1e30f, lrow = 0.f;

        const int ntiles = qt + 1;
        bf16x8 kreg[2], vreg[2];
#pragma unroll
        for (int c = 0; c < 2; ++c) {
            kreg[c] = *(const bf16x8*)&K[base + (size_t)(c * 32 + krow) * DHEAD + kcol];
            vreg[c] = *(const bf16x8*)&Vt[base + (size_t)(c * 32 + krow) * SEQ + kcol];
        }

        for (int t = 0; t < ntiles; ++t) {
            const int kv0 = t << 6;
            __syncthreads();                 // prev tile's LDS reads done
#pragma unroll
            for (int c = 0; c < 2; ++c) {    // stage K/V (swizzled)
                const int row = c * 32 + krow;
                const int g16 = (tid & 7) ^ (row & 7);
                *(bf16x8*)((char*)Ks + row * 128 + (g16 << 4)) = kreg[c];
                *(bf16x8*)((char*)Vs + row * 128 + (g16 << 4)) = vreg[c];
            }
            __syncthreads();
            if (t + 1 < ntiles) {            // prefetch next tile (T14)
                const int nv0 = kv0 + 64;
#pragma unroll
                for (int c = 0; c < 2; ++c) {
                    kreg[c] = *(const bf16x8*)&K[base + (size_t)(nv0 + c * 32 + krow) * DHEAD + kcol];
                    vreg[c] = *(const bf16x8*)&Vt[base + (size_t)(c * 32 + krow) * SEQ + nv0 + kcol];
                }
            }
            if (kv0 > qw0 + 15) continue;    // wave fully masked (barriers balanced)

            // ---- S^T = K Q^T : s[nj] rows kv=nj*16+hi*4+r, cols q=lo
            f32x4 s[4] = {};
            __builtin_amdgcn_s_setprio(1);
#pragma unroll
            for (int ks = 0; ks < 2; ++ks) {
                bf16x8 kf[4];
#pragma unroll
                for (int nj = 0; nj < 4; ++nj)
                    kf[nj] = *(const bf16x8*)((char*)Ks + (nj * 16 + lo) * 128 +
                                              ((((ks << 2) + hi) ^ sw) << 4));
#pragma unroll
                for (int nj = 0; nj < 4; ++nj)
                    s[nj] = __builtin_amdgcn_mfma_f32_16x16x32_bf16(
                        kf[nj], qf[ks], s[nj], 0, 0, 0);
            }
            __builtin_amdgcn_s_setprio(0);

            // ---- causal mask (diagonal tile only)
            if (kv0 + 63 > qw0) {
                const int gq = qw0 + lo;
#pragma unroll
                for (int nj = 0; nj < 4; ++nj)
#pragma unroll
                    for (int r = 0; r < 4; ++r) {
                        const int gk = kv0 + nj * 16 + hi * 4 + r;
                        if (gk > gq) s[nj][r] = -1e30f;
                    }
            }

            // ---- online softmax (q=lo lane-local), defer-max THR=8 (log2)
            float tl = s[0][0];
#pragma unroll
            for (int nj = 0; nj < 4; ++nj)
#pragma unroll
                for (int r = 0; r < 4; ++r) tl = fmaxf(tl, s[nj][r]);
            float corr = 1.f;
            if (__any(tl > mrow + 8.f)) {
                float m2 = fmaxf(tl, __shfl_xor(tl, 16));
                m2 = fmaxf(m2, __shfl_xor(m2, 32));
                const float mn = fmaxf(mrow, m2);
                corr = exp2_fast(mrow - mn);
                mrow = mn;
#pragma unroll
                for (int r = 0; r < 4; ++r) {
                    const float cb = __shfl(corr, hi * 4 + r);
#pragma unroll
                    for (int ni = 0; ni < 4; ++ni) o[ni][r] *= cb;
                }
            }

            float ls = 0.f;
#pragma unroll
            for (int nj = 0; nj < 4; ++nj) {
#pragma unroll
                for (int r = 0; r < 4; ++r) {
                    const float p = exp2_fast(s[nj][r] - mrow);
                    s[nj][r] = p;
                    ls += p;
                }
                uint2 pp;
                pp.x = cvt_pk_bf16(s[nj][0], s[nj][1]);
                pp.y = cvt_pk_bf16(s[nj][2], s[nj][3]);
                const int gP = ((nj << 1) + (hi >> 1)) ^ sw;
                *(uint2*)(PqW + lo * 128 + (gP << 4) + ((hi & 1) << 3)) = pp;
            }
            ls += __shfl_xor(ls, 16);
            ls += __shfl_xor(ls, 32);
            lrow = lrow * corr + ls;

            // ---- O += P V
            __builtin_amdgcn_s_setprio(1);
#pragma unroll
            for (int ks2 = 0; ks2 < 2; ++ks2) {
                bf16x8 pf, vf[4];
                pf = *(const bf16x8*)(PqW + lo * 128 +
                                      ((((ks2 << 2) + hi) ^ sw) << 4));
#pragma unroll
                for (int ni = 0; ni < 4; ++ni)
                    vf[ni] = *(const bf16x8*)((char*)Vs + (ni * 16 + lo) * 128 +
                                              ((((ks2 << 2) + hi) ^ sw) << 4));
#pragma unroll
                for (int ni = 0; ni < 4; ++ni)
                    o[ni] = __builtin_amdgcn_mfma_f32_16x16x32_bf16(
                        pf, vf[ni], o[ni], 0, 0, 0);
            }
            __builtin_amdgcn_s_setprio(0);
        }

        // ---- epilogue for this Q-tile
        const float rv = 1.0f / lrow;
#pragma unroll
        for (int r = 0; r < 4; ++r) {
            const float rb = __shfl(rv, hi * 4 + r);
            const int gq = qw0 + hi * 4 + r;
#pragma unroll
            for (int ni = 0; ni < 4; ++ni)
                ctx[((size_t)(b * SEQ + gq)) * D_MODEL + h * DHEAD + ni * 16 + lo] =
                    f2bf(o[ni][r] * rb);
        }
    }
}

// ---------------------------------------------------------------- launch
extern "C" void kernel_launch(void* const* d_in, const int* in_sizes, int n_in,
                              void* d_out, int out_size, void* d_ws, size_t ws_size,
                              hipStream_t stream) {
    const float* x  = (const float*)d_in[0];
    const float* Wq = (const float*)d_in[1];
    const float* bq = (const float*)d_in[2];
    const float* Wk = (const float*)d_in[3];
    const float* bk = (const float*)d_in[4];
    const float* Wv = (const float*)d_in[5];
    const float* bv = (const float*)d_in[6];
    const float* Wo = (const float*)d_in[7];
    const float* bo = (const float*)d_in[8];

    char* ws = (char*)d_ws;
    ushort* xb  = (ushort*)(ws);
    ushort* wb  = (ushort*)(ws + (16u << 20));
    ushort* Qb  = (ushort*)(ws + (24u << 20));
    ushort* Kb  = (ushort*)(ws + (40u << 20));
    ushort* Vtb = (ushort*)(ws + (56u << 20));
    ushort* ctx = (ushort*)(ws + (72u << 20));

    convert_kernel<<<2048, 256, 0, stream>>>(
        (const float4*)x, (const float4*)Wq, (const float4*)Wk,
        (const float4*)Wv, (const float4*)Wo, (ushort4*)xb, (ushort4*)wb);

    const int NW = D_MODEL * D_MODEL;
    const float qscale = 0.125f * 1.44269504f;   // fold log2e: softmax in exp2 domain

    gemm_qkv<<<1536, 256, 0, stream>>>(xb, wb, bq, bk, bv, Qb, Kb, Vtb, qscale);

    attn_kernel<<<1024, 256, 0, stream>>>(Qb, Kb, Vtb, ctx);

    gemm_out<<<dim3(8, 64), 256, 0, stream>>>(ctx, wb + 3 * NW, bo, (float*)d_out);
}